// Round 1
// baseline (238.509 us; speedup 1.0000x reference)
//
#include <hip/hip_runtime.h>

// ---------------------------------------------------------------------------
// MHA block: qkv = x@W_attn + b ; causal softmax((q k^T)/sqrt(C)) @ v ; @W_proj
// B=2 T=2048 C=1024 H=16 D=64.  All GEMM-shaped compute in bf16 MFMA
// (16x16x32), f32 accumulate.  Threshold is bf16-grade (7.16e-2).
// ---------------------------------------------------------------------------

typedef short bfrag __attribute__((ext_vector_type(8)));   // 8 bf16 bit-patterns
typedef float facc  __attribute__((ext_vector_type(4)));   // MFMA C/D
typedef float f4v   __attribute__((ext_vector_type(4)));
typedef unsigned int u32x2 __attribute__((ext_vector_type(2)));
typedef unsigned short u16;

#define MFMA16(a, b, c) __builtin_amdgcn_mfma_f32_16x16x32_bf16((a), (b), (c), 0, 0, 0)

__device__ __forceinline__ u16 f2bf(float f) {
  union { float f; unsigned u; } v; v.f = f;
  unsigned r = v.u + 0x7fffu + ((v.u >> 16) & 1u);   // round-to-nearest-even
  return (u16)(r >> 16);
}

__device__ __forceinline__ void async_lds16(const void* g, void* l) {
  __builtin_amdgcn_global_load_lds(
      (const __attribute__((address_space(1))) unsigned char*)g,
      (__attribute__((address_space(3))) unsigned char*)l, 16, 0, 0);
}

// --------------------------- prep kernels ----------------------------------

__global__ void cast_bf16_kernel(const float* __restrict__ s, u16* __restrict__ d, int n) {
  int i = (blockIdx.x * blockDim.x + threadIdx.x) * 4;
  if (i >= n) return;
  f4v v = *reinterpret_cast<const f4v*>(s + i);
  u32x2 w;
  w[0] = (unsigned)f2bf(v[0]) | ((unsigned)f2bf(v[1]) << 16);
  w[1] = (unsigned)f2bf(v[2]) | ((unsigned)f2bf(v[3]) << 16);
  *reinterpret_cast<u32x2*>(d + i) = w;
}

// dst[n][k] = (bf16) src[k][n];  src is [K][N] f32 row-major
__global__ void transpose_cast_kernel(const float* __restrict__ src, u16* __restrict__ dst,
                                      int K, int N) {
  __shared__ float tile[32][33];
  int tx = threadIdx.x, ty = threadIdx.y;
  int n0 = blockIdx.x * 32, k0 = blockIdx.y * 32;
  for (int j = ty; j < 32; j += 8)
    tile[j][tx] = src[(size_t)(k0 + j) * N + (n0 + tx)];
  __syncthreads();
  for (int j = ty; j < 32; j += 8)
    dst[(size_t)(n0 + j) * K + (k0 + tx)] = f2bf(tile[tx][j]);
}

// --------------------------- GEMM (m97-structure) --------------------------
// C[M,N] = A[M,1024] * Bt[N,1024]^T + bias.  128x128 tile, 4 waves (2x2),
// BK=32, global_load_lds width-16 staging, 16 MFMA / K-step.
// EPI 0: scatter into Q/K/V [B,H,T,D] bf16, Q scaled by 1/32.
// EPI 1: f32 out.

template <int EPI>
__global__ __launch_bounds__(256) void gemm_kernel(
    const u16* __restrict__ A, const u16* __restrict__ Bt,
    const float* __restrict__ bias, float* __restrict__ outf,
    u16* __restrict__ qb, u16* __restrict__ kb, u16* __restrict__ vb) {
  constexpr int KD = 1024;
  __shared__ u16 As[128 * 32];
  __shared__ u16 Bs[128 * 32];
  const int t = threadIdx.x;
  const int l = t & 63, w = t >> 6;
  const int wm = w >> 1, wn = w & 1;
  const int lg = l >> 4, lc = l & 15;
  const int m0 = blockIdx.y * 128, n0 = blockIdx.x * 128;
  facc acc[4][4] = {};
  const int srow = t >> 2, scol = (t & 3) * 8;      // staging: 16B per thread per call
  const u16* ga = A + (size_t)(m0 + srow) * KD + scol;
  const u16* gb = Bt + (size_t)(n0 + srow) * KD + scol;
  u16* la0 = As + t * 8;  u16* la1 = As + 2048 + t * 8;
  u16* lb0 = Bs + t * 8;  u16* lb1 = Bs + 2048 + t * 8;
  for (int kt = 0; kt < KD / 32; ++kt) {
    __syncthreads();
    async_lds16(ga + kt * 32, la0);
    async_lds16(ga + 64 * KD + kt * 32, la1);
    async_lds16(gb + kt * 32, lb0);
    async_lds16(gb + 64 * KD + kt * 32, lb1);
    __syncthreads();
    bfrag a[4], b[4];
#pragma unroll
    for (int mi = 0; mi < 4; ++mi)
      a[mi] = *reinterpret_cast<const bfrag*>(As + (wm * 64 + mi * 16 + lc) * 32 + lg * 8);
#pragma unroll
    for (int ni = 0; ni < 4; ++ni)
      b[ni] = *reinterpret_cast<const bfrag*>(Bs + (wn * 64 + ni * 16 + lc) * 32 + lg * 8);
#pragma unroll
    for (int mi = 0; mi < 4; ++mi)
#pragma unroll
      for (int ni = 0; ni < 4; ++ni)
        acc[mi][ni] = MFMA16(a[mi], b[ni], acc[mi][ni]);
  }
  // epilogue: C/D layout col = l&15, row = 4*(l>>4)+reg  (m89-verified)
#pragma unroll
  for (int mi = 0; mi < 4; ++mi) {
#pragma unroll
    for (int ni = 0; ni < 4; ++ni) {
#pragma unroll
      for (int r = 0; r < 4; ++r) {
        int gm = m0 + wm * 64 + mi * 16 + lg * 4 + r;
        int gn = n0 + wn * 64 + ni * 16 + lc;
        float val = acc[mi][ni][r] + bias[gn];
        if constexpr (EPI == 0) {
          int sec = gn >> 10, ci = gn & 1023;
          int h = ci >> 6, d = ci & 63;
          int b_ = gm >> 11, tq = gm & 2047;
          size_t idx = ((size_t)(b_ * 16 + h) * 2048 + tq) * 64 + d;
          if (sec == 0)      qb[idx] = f2bf(val * 0.03125f);  // fold 1/sqrt(C) into Q
          else if (sec == 1) kb[idx] = f2bf(val);
          else               vb[idx] = f2bf(val);
        } else {
          outf[(size_t)gm * 1024 + gn] = val;
        }
      }
    }
  }
}

// --------------------------- flash attention -------------------------------
// grid: (B*H) * (T/64) blocks; 4 waves, each owns 16 q-rows. KVBLK=64.
// K staged [kv][d] (pad 88), V staged transposed [d][kv] (pad 88),
// P per-wave LDS round-trip to re-fragment for PV.

__global__ __launch_bounds__(256) void attn_kernel(
    const u16* __restrict__ Qb, const u16* __restrict__ Kb, const u16* __restrict__ Vb,
    u16* __restrict__ attn) {
  constexpr int T = 2048, D = 64, PAD = 88;
  __shared__ u16 Ks[64 * PAD];
  __shared__ u16 Vt[64 * PAD];
  __shared__ u16 Ps[4 * 16 * PAD];
  const int t = threadIdx.x;
  const int l = t & 63, w = t >> 6;
  const int lg = l >> 4, lc = l & 15;
  const int bid = blockIdx.x;
  const int qt = bid & 31;           // T/64 = 32 q-tiles
  const int bh = bid >> 5;           // b*16 + h
  const size_t hb = (size_t)bh * T * D;
  const u16* Qp = Qb + hb;
  const u16* Kp = Kb + hb;
  const u16* Vp = Vb + hb;
  const int qr0 = qt * 64 + w * 16;
  bfrag aq[2];
  aq[0] = *reinterpret_cast<const bfrag*>(Qp + (size_t)(qr0 + lc) * D + lg * 8);
  aq[1] = *reinterpret_cast<const bfrag*>(Qp + (size_t)(qr0 + lc) * D + 32 + lg * 8);
  facc acc[4] = {};                  // O accum, 4 d-chunks
  float m_r[4], l_r[4];
#pragma unroll
  for (int r = 0; r < 4; ++r) { m_r[r] = -1e30f; l_r[r] = 0.f; }
  u16* Psw = Ps + w * 16 * PAD;
  const int ntiles = qt + 1;
  for (int it = 0; it < ntiles; ++it) {
    const int kvb = it * 64;
    __syncthreads();                 // previous tile's LDS reads done
    for (int c = t; c < 512; c += 256) {
      int row = c >> 3, c8 = c & 7;
      bfrag k8 = *reinterpret_cast<const bfrag*>(Kp + (size_t)(kvb + row) * D + c8 * 8);
      *reinterpret_cast<bfrag*>(Ks + row * PAD + c8 * 8) = k8;
      bfrag v8 = *reinterpret_cast<const bfrag*>(Vp + (size_t)(kvb + row) * D + c8 * 8);
#pragma unroll
      for (int j = 0; j < 8; ++j) Vt[(c8 * 8 + j) * PAD + row] = (u16)v8[j];
    }
    __syncthreads();
    // S = Q K^T  (A = Q rows, B = Ks rows as K^T)
    facc s[4] = {};
#pragma unroll
    for (int nc = 0; nc < 4; ++nc)
#pragma unroll
      for (int ks = 0; ks < 2; ++ks) {
        bfrag bk = *reinterpret_cast<const bfrag*>(Ks + (nc * 16 + lc) * PAD + ks * 32 + lg * 8);
        s[nc] = MFMA16(aq[ks], bk, s[nc]);
      }
    if (it == ntiles - 1) {          // diagonal tile: causal mask
#pragma unroll
      for (int nc = 0; nc < 4; ++nc)
#pragma unroll
        for (int r = 0; r < 4; ++r)
          if (kvb + nc * 16 + lc > qr0 + lg * 4 + r) s[nc][r] = -1e30f;
    }
    // online softmax; rows live in 16-lane groups (same l>>4)
#pragma unroll
    for (int r = 0; r < 4; ++r) {
      float pm = fmaxf(fmaxf(s[0][r], s[1][r]), fmaxf(s[2][r], s[3][r]));
#pragma unroll
      for (int mk = 1; mk <= 8; mk <<= 1) pm = fmaxf(pm, __shfl_xor(pm, mk));
      float mn = fmaxf(m_r[r], pm);
      float al = __expf(m_r[r] - mn);
      float ps = 0.f;
#pragma unroll
      for (int nc = 0; nc < 4; ++nc) {
        float p = __expf(s[nc][r] - mn);
        ps += p;
        Psw[(lg * 4 + r) * PAD + nc * 16 + lc] = f2bf(p);
      }
#pragma unroll
      for (int mk = 1; mk <= 8; mk <<= 1) ps += __shfl_xor(ps, mk);
      l_r[r] = l_r[r] * al + ps;
      m_r[r] = mn;
#pragma unroll
      for (int nc = 0; nc < 4; ++nc) acc[nc][r] *= al;
    }
    asm volatile("s_waitcnt lgkmcnt(0)" ::: "memory");   // P writes visible wave-wide
    bfrag ap[2];
    ap[0] = *reinterpret_cast<const bfrag*>(Psw + lc * PAD + lg * 8);
    ap[1] = *reinterpret_cast<const bfrag*>(Psw + lc * PAD + 32 + lg * 8);
#pragma unroll
    for (int nc = 0; nc < 4; ++nc)
#pragma unroll
      for (int ks = 0; ks < 2; ++ks) {
        bfrag bv = *reinterpret_cast<const bfrag*>(Vt + (nc * 16 + lc) * PAD + ks * 32 + lg * 8);
        acc[nc] = MFMA16(ap[ks], bv, acc[nc]);
      }
  }
  const int b_ = bh >> 4, h = bh & 15;
#pragma unroll
  for (int nc = 0; nc < 4; ++nc)
#pragma unroll
    for (int r = 0; r < 4; ++r) {
      float o = acc[nc][r] / l_r[r];
      int tq = qr0 + lg * 4 + r;
      int col = h * 64 + nc * 16 + lc;
      attn[(size_t)(b_ * T + tq) * 1024 + col] = f2bf(o);
    }
}

// --------------------------- launcher --------------------------------------

extern "C" void kernel_launch(void* const* d_in, const int* in_sizes, int n_in,
                              void* d_out, int out_size, void* d_ws, size_t ws_size,
                              hipStream_t stream) {
  const float* x      = (const float*)d_in[0];
  const float* W_attn = (const float*)d_in[1];
  const float* b_attn = (const float*)d_in[2];
  const float* W_proj = (const float*)d_in[3];
  const float* b_proj = (const float*)d_in[4];
  float* out = (float*)d_out;
  char* ws = (char*)d_ws;
  // ws layout (48 MiB total)
  u16* xb   = (u16*)(ws);                       // [4096][1024] bf16   8 MiB
  u16* Wat  = (u16*)(ws + (8u  << 20));         // [3072][1024] bf16   6 MiB
  u16* Wpt  = (u16*)(ws + (14u << 20));         // [1024][1024] bf16   2 MiB
  u16* Qb   = (u16*)(ws + (16u << 20));         // [B,H,T,D] bf16      8 MiB
  u16* Kb   = (u16*)(ws + (24u << 20));         //                     8 MiB
  u16* Vb   = (u16*)(ws + (32u << 20));         //                     8 MiB
  u16* attn = (u16*)(ws + (40u << 20));         // [4096][1024] bf16   8 MiB

  cast_bf16_kernel<<<4096, 256, 0, stream>>>(x, xb, 4096 * 1024);
  transpose_cast_kernel<<<dim3(96, 32), dim3(32, 8), 0, stream>>>(W_attn, Wat, 1024, 3072);
  transpose_cast_kernel<<<dim3(32, 32), dim3(32, 8), 0, stream>>>(W_proj, Wpt, 1024, 1024);
  gemm_kernel<0><<<dim3(24, 32), 256, 0, stream>>>(xb, Wat, b_attn, nullptr, Qb, Kb, Vb);
  attn_kernel<<<1024, 256, 0, stream>>>(Qb, Kb, Vb, attn);
  gemm_kernel<1><<<dim3(8, 32), 256, 0, stream>>>(attn, Wpt, b_proj, out, nullptr, nullptr, nullptr);
}

// Round 2
// 178.136 us; speedup vs baseline: 1.3389x; 1.3389x over previous
//
#include <hip/hip_runtime.h>

// ---------------------------------------------------------------------------
// MHA block: qkv = x@W_attn + b ; causal softmax((q k^T)/sqrt(C)) @ v ; @W_proj
// B=2 T=2048 C=1024 H=16 D=64.  bf16 MFMA, f32 accumulate.
// R2: swapped-QK 32x32 flash attention (in-register softmax, cvt_pk+permlane
// P re-fragmentation, V^T precomputed by GEMM1 epilogue, double-buffered LDS).
// ---------------------------------------------------------------------------

typedef short bfrag __attribute__((ext_vector_type(8)));   // 8 bf16 bit-patterns
typedef float facc  __attribute__((ext_vector_type(4)));   // 16x16 MFMA C/D
typedef float f16v  __attribute__((ext_vector_type(16)));  // 32x32 MFMA C/D
typedef float f4v   __attribute__((ext_vector_type(4)));
typedef unsigned int u32x2 __attribute__((ext_vector_type(2)));
typedef unsigned int u32x4v __attribute__((ext_vector_type(4)));
typedef unsigned short u16;

#define MFMA16(a, b, c) __builtin_amdgcn_mfma_f32_16x16x32_bf16((a), (b), (c), 0, 0, 0)
#define MFMA32(a, b, c) __builtin_amdgcn_mfma_f32_32x32x16_bf16((a), (b), (c), 0, 0, 0)

__device__ __forceinline__ u16 f2bf(float f) {
  union { float f; unsigned u; } v; v.f = f;
  unsigned r = v.u + 0x7fffu + ((v.u >> 16) & 1u);   // round-to-nearest-even
  return (u16)(r >> 16);
}

__device__ __forceinline__ unsigned cvtpk(float lo, float hi) {
  unsigned r;
  asm("v_cvt_pk_bf16_f32 %0, %1, %2" : "=v"(r) : "v"(lo), "v"(hi));
  return r;
}

__device__ __forceinline__ void async_lds16(const void* g, void* l) {
  __builtin_amdgcn_global_load_lds(
      (const __attribute__((address_space(1))) unsigned char*)g,
      (__attribute__((address_space(3))) unsigned char*)l, 16, 0, 0);
}

// --------------------------- prep kernels ----------------------------------

__global__ void cast_bf16_kernel(const float* __restrict__ s, u16* __restrict__ d, int n) {
  int i = (blockIdx.x * blockDim.x + threadIdx.x) * 4;
  if (i >= n) return;
  f4v v = *reinterpret_cast<const f4v*>(s + i);
  u32x2 w;
  w[0] = (unsigned)f2bf(v[0]) | ((unsigned)f2bf(v[1]) << 16);
  w[1] = (unsigned)f2bf(v[2]) | ((unsigned)f2bf(v[3]) << 16);
  *reinterpret_cast<u32x2*>(d + i) = w;
}

// dst[n][k] = (bf16) src[k][n];  src is [K][N] f32 row-major
__global__ void transpose_cast_kernel(const float* __restrict__ src, u16* __restrict__ dst,
                                      int K, int N) {
  __shared__ float tile[32][33];
  int tx = threadIdx.x, ty = threadIdx.y;
  int n0 = blockIdx.x * 32, k0 = blockIdx.y * 32;
  for (int j = ty; j < 32; j += 8)
    tile[j][tx] = src[(size_t)(k0 + j) * N + (n0 + tx)];
  __syncthreads();
  for (int j = ty; j < 32; j += 8)
    dst[(size_t)(n0 + j) * K + (k0 + tx)] = f2bf(tile[tx][j]);
}

// --------------------------- GEMM (m97-structure) --------------------------
// C[M,N] = A[M,1024] * Bt[N,1024]^T + bias.  128x128 tile, 4 waves (2x2),
// BK=32, global_load_lds width-16 staging, 16 MFMA / K-step.
// EPI 0: scatter into Q [b,h,t,d] (scaled by log2e/32), K [b,h,t,d],
//        V^T [b,h,d,t]  (all bf16).
// EPI 1: f32 out.

template <int EPI>
__global__ __launch_bounds__(256) void gemm_kernel(
    const u16* __restrict__ A, const u16* __restrict__ Bt,
    const float* __restrict__ bias, float* __restrict__ outf,
    u16* __restrict__ qb, u16* __restrict__ kb, u16* __restrict__ vb) {
  constexpr int KD = 1024;
  __shared__ u16 As[128 * 32];
  __shared__ u16 Bs[128 * 32];
  const int t = threadIdx.x;
  const int l = t & 63, w = t >> 6;
  const int wm = w >> 1, wn = w & 1;
  const int lg = l >> 4, lc = l & 15;
  const int m0 = blockIdx.y * 128, n0 = blockIdx.x * 128;
  facc acc[4][4] = {};
  const int srow = t >> 2, scol = (t & 3) * 8;      // staging: 16B per thread per call
  const u16* ga = A + (size_t)(m0 + srow) * KD + scol;
  const u16* gb = Bt + (size_t)(n0 + srow) * KD + scol;
  u16* la0 = As + t * 8;  u16* la1 = As + 2048 + t * 8;
  u16* lb0 = Bs + t * 8;  u16* lb1 = Bs + 2048 + t * 8;
  for (int kt = 0; kt < KD / 32; ++kt) {
    __syncthreads();
    async_lds16(ga + kt * 32, la0);
    async_lds16(ga + 64 * KD + kt * 32, la1);
    async_lds16(gb + kt * 32, lb0);
    async_lds16(gb + 64 * KD + kt * 32, lb1);
    __syncthreads();
    bfrag a[4], b[4];
#pragma unroll
    for (int mi = 0; mi < 4; ++mi)
      a[mi] = *reinterpret_cast<const bfrag*>(As + (wm * 64 + mi * 16 + lc) * 32 + lg * 8);
#pragma unroll
    for (int ni = 0; ni < 4; ++ni)
      b[ni] = *reinterpret_cast<const bfrag*>(Bs + (wn * 64 + ni * 16 + lc) * 32 + lg * 8);
#pragma unroll
    for (int mi = 0; mi < 4; ++mi)
#pragma unroll
      for (int ni = 0; ni < 4; ++ni)
        acc[mi][ni] = MFMA16(a[mi], b[ni], acc[mi][ni]);
  }
  // epilogue: C/D layout col = l&15, row = 4*(l>>4)+reg  (m89-verified)
#pragma unroll
  for (int mi = 0; mi < 4; ++mi) {
#pragma unroll
    for (int ni = 0; ni < 4; ++ni) {
#pragma unroll
      for (int r = 0; r < 4; ++r) {
        int gm = m0 + wm * 64 + mi * 16 + lg * 4 + r;
        int gn = n0 + wn * 64 + ni * 16 + lc;
        float val = acc[mi][ni][r] + bias[gn];
        if constexpr (EPI == 0) {
          int sec = gn >> 10, ci = gn & 1023;
          int h = ci >> 6, d = ci & 63;
          int b_ = gm >> 11, tq = gm & 2047;
          int bh = b_ * 16 + h;
          if (sec == 0) {
            // fold (1/sqrt(C)) * log2(e) into Q for exp2-domain softmax
            qb[((size_t)bh * 2048 + tq) * 64 + d] = f2bf(val * 0.045084439f);
          } else if (sec == 1) {
            kb[((size_t)bh * 2048 + tq) * 64 + d] = f2bf(val);
          } else {
            // V stored TRANSPOSED: [bh][d][t]
            vb[((size_t)bh * 64 + d) * 2048 + tq] = f2bf(val);
          }
        } else {
          outf[(size_t)gm * 1024 + gn] = val;
        }
      }
    }
  }
}

// --------------------------- flash attention -------------------------------
// Swapped-QK 32x32 structure (m214-style):
//   S^T = mfma32(A=K, B=Q): lane owns one q-column (q = q0 + 32*qb + (l&31)),
//   k rows (reg&3)+8*(reg>>2)+4*(l>>5) per 32-k tile -> softmax in-register.
//   P -> PV A-fragment via v_cvt_pk_bf16_f32 + v_permlane32_swap_b32.
//   V^T staged from global [bh][d][t]; K row-major.  KVBLK=64, QBLK=128,
//   2 waves x 64 q-rows, double-buffered LDS, one barrier per kv tile.
// Grid 512: bh = b&31 (XCD-locked), tile pairing (b, b+256) -> (15-x, x).

__global__ __launch_bounds__(128, 1) void attn_kernel(
    const u16* __restrict__ Qb, const u16* __restrict__ Kb,
    const u16* __restrict__ Vtb, u16* __restrict__ attn) {
  constexpr int T = 2048, PAD = 72;
  __shared__ u16 Ks[2][64 * PAD];
  __shared__ u16 Vs[2][64 * PAD];     // V^T tile: [d][kv]
  const int t = threadIdx.x;
  const int l = t & 63, w = t >> 6;
  const int c = l & 31, h = l >> 5;
  const int b = blockIdx.x;
  const int bh = b & 31;
  const int ti = (b >> 5) & 7;
  const int tile = (b >> 8) ? ti : 15 - ti;    // long tiles dispatched first
  const int ntile = 2 * tile + 2;
  const size_t base = (size_t)bh * T * 64;
  const u16* Qp = Qb + base;
  const u16* Kp = Kb + base;
  const u16* Vp = Vtb + base;                  // [d][T]
  const int q0 = tile * 128 + w * 64;

  // Q fragments (B-operand of QK): qf[qb][dt], elem j = Q[q0+32qb+c][16dt+8h+j]
  bfrag qf[2][4];
#pragma unroll
  for (int qb = 0; qb < 2; ++qb)
#pragma unroll
    for (int dt = 0; dt < 4; ++dt)
      qf[qb][dt] = *reinterpret_cast<const bfrag*>(
          Qp + (size_t)(q0 + 32 * qb + c) * 64 + dt * 16 + 8 * h);

  f16v o[2][2] = {};                 // [qb][nt] output accum
  float m_[2] = {-1e30f, -1e30f}, l_[2] = {0.f, 0.f};

  // staging geometry: 512 16B-chunks per 64x64 tile, 128 threads -> 4 each
  int srow[4], scol8[4];
#pragma unroll
  for (int i = 0; i < 4; ++i) {
    int cc = t + 128 * i;
    srow[i] = cc >> 3; scol8[i] = (cc & 7) * 8;
  }
  bfrag kst[4], vst[4];
  // prologue: stage tile 0
#pragma unroll
  for (int i = 0; i < 4; ++i) {
    kst[i] = *reinterpret_cast<const bfrag*>(Kp + (size_t)srow[i] * 64 + scol8[i]);
    vst[i] = *reinterpret_cast<const bfrag*>(Vp + (size_t)srow[i] * T + scol8[i]);
  }
#pragma unroll
  for (int i = 0; i < 4; ++i) {
    *reinterpret_cast<bfrag*>(&Ks[0][srow[i] * PAD + scol8[i]]) = kst[i];
    *reinterpret_cast<bfrag*>(&Vs[0][srow[i] * PAD + scol8[i]]) = vst[i];
  }
  __syncthreads();

  for (int it = 0; it < ntile; ++it) {
    const int cur = it & 1;
    const int kvb = 64 * it;
    if (it + 1 < ntile) {              // issue next-tile loads early (T14)
      const int nb = 64 * (it + 1);
#pragma unroll
      for (int i = 0; i < 4; ++i) {
        kst[i] = *reinterpret_cast<const bfrag*>(Kp + (size_t)(nb + srow[i]) * 64 + scol8[i]);
        vst[i] = *reinterpret_cast<const bfrag*>(Vp + (size_t)srow[i] * T + nb + scol8[i]);
      }
    }
    const u16* ks = Ks[cur];
    const u16* vs = Vs[cur];

    // ---- S^T = K * Q : s[qb][kt], lane col q = q0+32qb+c ----
    f16v s[2][2] = {};
#pragma unroll
    for (int kt = 0; kt < 2; ++kt)
#pragma unroll
      for (int dt = 0; dt < 4; ++dt) {
        const bfrag a = *reinterpret_cast<const bfrag*>(ks + (32 * kt + c) * PAD + dt * 16 + 8 * h);
        s[0][kt] = MFMA32(a, qf[0][dt], s[0][kt]);
        s[1][kt] = MFMA32(a, qf[1][dt], s[1][kt]);
      }

    // ---- causal mask (diagonal tiles only) ----
    if (kvb + 63 > q0) {
#pragma unroll
      for (int qb = 0; qb < 2; ++qb) {
        const int qq = q0 + 32 * qb + c;
#pragma unroll
        for (int kt = 0; kt < 2; ++kt)
#pragma unroll
          for (int r = 0; r < 16; ++r) {
            const int kk = kvb + 32 * kt + (r & 3) + 8 * (r >> 2) + 4 * h;
            if (kk > qq) s[qb][kt][r] = -1e30f;
          }
      }
    }

    // ---- online softmax, in-register (exp2 domain) ----
#pragma unroll
    for (int qb = 0; qb < 2; ++qb) {
      float pm = -1e30f;
#pragma unroll
      for (int kt = 0; kt < 2; ++kt)
#pragma unroll
        for (int r = 0; r < 16; ++r) pm = fmaxf(pm, s[qb][kt][r]);
      pm = fmaxf(pm, __shfl_xor(pm, 32));
      if (!__all(pm <= m_[qb] + 8.0f)) {     // T13 defer-max, THR=8 (2^8=256 ok in bf16)
        const float mn = fmaxf(m_[qb], pm);
        const float al = exp2f(m_[qb] - mn);
        l_[qb] *= al;
#pragma unroll
        for (int r = 0; r < 16; ++r) {
          const float ar = __shfl(al, (r & 3) + 8 * (r >> 2) + 4 * h);
          o[qb][0][r] *= ar;
          o[qb][1][r] *= ar;
        }
        m_[qb] = mn;
      }
      float ps = 0.f;
#pragma unroll
      for (int kt = 0; kt < 2; ++kt)
#pragma unroll
        for (int r = 0; r < 16; ++r) {
          const float e = exp2f(s[qb][kt][r] - m_[qb]);
          s[qb][kt][r] = e;
          ps += e;
        }
      ps += __shfl_xor(ps, 32);
      l_[qb] += ps;
    }

    // ---- P -> A-fragments: 16 cvt_pk + 8 permlane32_swap per qb ----
    bfrag pa[2][4];
#pragma unroll
    for (int qb = 0; qb < 2; ++qb)
#pragma unroll
      for (int kt = 0; kt < 2; ++kt)
#pragma unroll
        for (int sub = 0; sub < 2; ++sub) {
          const int bs = 8 * sub;
          unsigned x1 = cvtpk(s[qb][kt][bs + 0], s[qb][kt][bs + 1]);
          unsigned y1 = cvtpk(s[qb][kt][bs + 4], s[qb][kt][bs + 5]);
          asm volatile("v_permlane32_swap_b32 %0, %1" : "+v"(x1), "+v"(y1));
          unsigned x2 = cvtpk(s[qb][kt][bs + 2], s[qb][kt][bs + 3]);
          unsigned y2 = cvtpk(s[qb][kt][bs + 6], s[qb][kt][bs + 7]);
          asm volatile("v_permlane32_swap_b32 %0, %1" : "+v"(x2), "+v"(y2));
          union { u32x4v wv; bfrag f; } u;
          u.wv[0] = x1; u.wv[1] = x2; u.wv[2] = y1; u.wv[3] = y2;
          pa[qb][2 * kt + sub] = u.f;
        }

    // ---- O += P * V  (B-operand from V^T LDS) ----
#pragma unroll
    for (int nt = 0; nt < 2; ++nt)
#pragma unroll
      for (int k2 = 0; k2 < 4; ++k2) {
        const bfrag bv = *reinterpret_cast<const bfrag*>(vs + (32 * nt + c) * PAD + 16 * k2 + 8 * h);
        o[0][nt] = MFMA32(pa[0][k2], bv, o[0][nt]);
        o[1][nt] = MFMA32(pa[1][k2], bv, o[1][nt]);
      }

    // ---- write next tile into other buffer; single barrier per iter ----
    if (it + 1 < ntile) {
      const int nxt = cur ^ 1;
#pragma unroll
      for (int i = 0; i < 4; ++i) {
        *reinterpret_cast<bfrag*>(&Ks[nxt][srow[i] * PAD + scol8[i]]) = kst[i];
        *reinterpret_cast<bfrag*>(&Vs[nxt][srow[i] * PAD + scol8[i]]) = vst[i];
      }
    }
    __syncthreads();
  }

  // ---- epilogue: O / l, write [b][t][h*64+d] bf16 ----
  const int b_ = bh >> 4, hd = bh & 15;
#pragma unroll
  for (int qb = 0; qb < 2; ++qb) {
    const float linv = 1.0f / l_[qb];
#pragma unroll
    for (int r = 0; r < 16; ++r) {
      const int row = (r & 3) + 8 * (r >> 2) + 4 * h;
      const float lr = __shfl(linv, row);
      const int tq = q0 + 32 * qb + row;
#pragma unroll
      for (int nt = 0; nt < 2; ++nt) {
        const int col = hd * 64 + 32 * nt + c;
        attn[((size_t)(b_ * T + tq)) * 1024 + col] = f2bf(o[qb][nt][r] * lr);
      }
    }
  }
}

// --------------------------- launcher --------------------------------------

extern "C" void kernel_launch(void* const* d_in, const int* in_sizes, int n_in,
                              void* d_out, int out_size, void* d_ws, size_t ws_size,
                              hipStream_t stream) {
  const float* x      = (const float*)d_in[0];
  const float* W_attn = (const float*)d_in[1];
  const float* b_attn = (const float*)d_in[2];
  const float* W_proj = (const float*)d_in[3];
  const float* b_proj = (const float*)d_in[4];
  float* out = (float*)d_out;
  char* ws = (char*)d_ws;
  // ws layout (48 MiB total)
  u16* xb   = (u16*)(ws);                       // [4096][1024] bf16   8 MiB
  u16* Wat  = (u16*)(ws + (8u  << 20));         // [3072][1024] bf16   6 MiB
  u16* Wpt  = (u16*)(ws + (14u << 20));         // [1024][1024] bf16   2 MiB
  u16* Qb   = (u16*)(ws + (16u << 20));         // [bh][t][d] bf16     8 MiB
  u16* Kb   = (u16*)(ws + (24u << 20));         // [bh][t][d]          8 MiB
  u16* Vtb  = (u16*)(ws + (32u << 20));         // [bh][d][t] (V^T)    8 MiB
  u16* attn = (u16*)(ws + (40u << 20));         // [4096][1024] bf16   8 MiB

  cast_bf16_kernel<<<4096, 256, 0, stream>>>(x, xb, 4096 * 1024);
  transpose_cast_kernel<<<dim3(96, 32), dim3(32, 8), 0, stream>>>(W_attn, Wat, 1024, 3072);
  transpose_cast_kernel<<<dim3(32, 32), dim3(32, 8), 0, stream>>>(W_proj, Wpt, 1024, 1024);
  gemm_kernel<0><<<dim3(24, 32), 256, 0, stream>>>(xb, Wat, b_attn, nullptr, Qb, Kb, Vtb);
  attn_kernel<<<512, 128, 0, stream>>>(Qb, Kb, Vtb, attn);
  gemm_kernel<1><<<dim3(8, 32), 256, 0, stream>>>(attn, Wpt, b_proj, out, nullptr, nullptr, nullptr);
}

// Round 3
// 137.745 us; speedup vs baseline: 1.7315x; 1.2932x over previous
//
#include <hip/hip_runtime.h>

// ---------------------------------------------------------------------------
// MHA block: qkv = x@W_attn + b ; causal softmax((q k^T)/sqrt(C)) @ v ; @W_proj
// B=2 T=2048 C=1024 H=16 D=64.  bf16 MFMA, f32 accumulate.
// R3: attention occupancy fix — QBLK=64, 32 q-rows/wave, grid 1024x128
// (4 blocks/CU, 8 waves/CU), global_load_lds staging with pre-swizzled
// global source (linear LDS dest, XOR chunk^(row&7) on source+read).
// ---------------------------------------------------------------------------

typedef short bfrag __attribute__((ext_vector_type(8)));   // 8 bf16 bit-patterns
typedef float facc  __attribute__((ext_vector_type(4)));   // 16x16 MFMA C/D
typedef float f16v  __attribute__((ext_vector_type(16)));  // 32x32 MFMA C/D
typedef float f4v   __attribute__((ext_vector_type(4)));
typedef unsigned int u32x2 __attribute__((ext_vector_type(2)));
typedef unsigned int u32x4v __attribute__((ext_vector_type(4)));
typedef unsigned short u16;

#define MFMA16(a, b, c) __builtin_amdgcn_mfma_f32_16x16x32_bf16((a), (b), (c), 0, 0, 0)
#define MFMA32(a, b, c) __builtin_amdgcn_mfma_f32_32x32x16_bf16((a), (b), (c), 0, 0, 0)

__device__ __forceinline__ u16 f2bf(float f) {
  union { float f; unsigned u; } v; v.f = f;
  unsigned r = v.u + 0x7fffu + ((v.u >> 16) & 1u);   // round-to-nearest-even
  return (u16)(r >> 16);
}

__device__ __forceinline__ unsigned cvtpk(float lo, float hi) {
  unsigned r;
  asm("v_cvt_pk_bf16_f32 %0, %1, %2" : "=v"(r) : "v"(lo), "v"(hi));
  return r;
}

__device__ __forceinline__ void async_lds16(const void* g, void* l) {
  __builtin_amdgcn_global_load_lds(
      (const __attribute__((address_space(1))) unsigned char*)g,
      (__attribute__((address_space(3))) unsigned char*)l, 16, 0, 0);
}

// --------------------------- prep kernels ----------------------------------

__global__ void cast_bf16_kernel(const float* __restrict__ s, u16* __restrict__ d, int n) {
  int i = (blockIdx.x * blockDim.x + threadIdx.x) * 4;
  if (i >= n) return;
  f4v v = *reinterpret_cast<const f4v*>(s + i);
  u32x2 w;
  w[0] = (unsigned)f2bf(v[0]) | ((unsigned)f2bf(v[1]) << 16);
  w[1] = (unsigned)f2bf(v[2]) | ((unsigned)f2bf(v[3]) << 16);
  *reinterpret_cast<u32x2*>(d + i) = w;
}

// dst[n][k] = (bf16) src[k][n];  src is [K][N] f32 row-major
__global__ void transpose_cast_kernel(const float* __restrict__ src, u16* __restrict__ dst,
                                      int K, int N) {
  __shared__ float tile[32][33];
  int tx = threadIdx.x, ty = threadIdx.y;
  int n0 = blockIdx.x * 32, k0 = blockIdx.y * 32;
  for (int j = ty; j < 32; j += 8)
    tile[j][tx] = src[(size_t)(k0 + j) * N + (n0 + tx)];
  __syncthreads();
  for (int j = ty; j < 32; j += 8)
    dst[(size_t)(n0 + j) * K + (k0 + tx)] = f2bf(tile[tx][j]);
}

// --------------------------- GEMM (m97-structure) --------------------------
// C[M,N] = A[M,1024] * Bt[N,1024]^T + bias.  128x128 tile, 4 waves (2x2),
// BK=32, global_load_lds width-16 staging, 16 MFMA / K-step.
// EPI 0: scatter into Q [bh,t,d] (scaled by log2e/32), K [bh,t,d],
//        V^T [bh,d,t]  (all bf16, unswizzled).
// EPI 1: f32 out.

template <int EPI>
__global__ __launch_bounds__(256) void gemm_kernel(
    const u16* __restrict__ A, const u16* __restrict__ Bt,
    const float* __restrict__ bias, float* __restrict__ outf,
    u16* __restrict__ qb, u16* __restrict__ kb, u16* __restrict__ vb) {
  constexpr int KD = 1024;
  __shared__ u16 As[128 * 32];
  __shared__ u16 Bs[128 * 32];
  const int t = threadIdx.x;
  const int l = t & 63, w = t >> 6;
  const int wm = w >> 1, wn = w & 1;
  const int lg = l >> 4, lc = l & 15;
  const int m0 = blockIdx.y * 128, n0 = blockIdx.x * 128;
  facc acc[4][4] = {};
  const int srow = t >> 2, scol = (t & 3) * 8;      // staging: 16B per thread per call
  const u16* ga = A + (size_t)(m0 + srow) * KD + scol;
  const u16* gb = Bt + (size_t)(n0 + srow) * KD + scol;
  u16* la0 = As + t * 8;  u16* la1 = As + 2048 + t * 8;
  u16* lb0 = Bs + t * 8;  u16* lb1 = Bs + 2048 + t * 8;
  for (int kt = 0; kt < KD / 32; ++kt) {
    __syncthreads();
    async_lds16(ga + kt * 32, la0);
    async_lds16(ga + 64 * KD + kt * 32, la1);
    async_lds16(gb + kt * 32, lb0);
    async_lds16(gb + 64 * KD + kt * 32, lb1);
    __syncthreads();
    bfrag a[4], b[4];
#pragma unroll
    for (int mi = 0; mi < 4; ++mi)
      a[mi] = *reinterpret_cast<const bfrag*>(As + (wm * 64 + mi * 16 + lc) * 32 + lg * 8);
#pragma unroll
    for (int ni = 0; ni < 4; ++ni)
      b[ni] = *reinterpret_cast<const bfrag*>(Bs + (wn * 64 + ni * 16 + lc) * 32 + lg * 8);
#pragma unroll
    for (int mi = 0; mi < 4; ++mi)
#pragma unroll
      for (int ni = 0; ni < 4; ++ni)
        acc[mi][ni] = MFMA16(a[mi], b[ni], acc[mi][ni]);
  }
  // epilogue: C/D layout col = l&15, row = 4*(l>>4)+reg  (m89-verified)
#pragma unroll
  for (int mi = 0; mi < 4; ++mi) {
#pragma unroll
    for (int ni = 0; ni < 4; ++ni) {
#pragma unroll
      for (int r = 0; r < 4; ++r) {
        int gm = m0 + wm * 64 + mi * 16 + lg * 4 + r;
        int gn = n0 + wn * 64 + ni * 16 + lc;
        float val = acc[mi][ni][r] + bias[gn];
        if constexpr (EPI == 0) {
          int sec = gn >> 10, ci = gn & 1023;
          int h = ci >> 6, d = ci & 63;
          int b_ = gm >> 11, tq = gm & 2047;
          int bh = b_ * 16 + h;
          if (sec == 0) {
            // fold (1/sqrt(C)) * log2(e) into Q for exp2-domain softmax
            qb[((size_t)bh * 2048 + tq) * 64 + d] = f2bf(val * 0.045084439f);
          } else if (sec == 1) {
            kb[((size_t)bh * 2048 + tq) * 64 + d] = f2bf(val);
          } else {
            // V stored TRANSPOSED: [bh][d][t]
            vb[((size_t)bh * 64 + d) * 2048 + tq] = f2bf(val);
          }
        } else {
          outf[(size_t)gm * 1024 + gn] = val;
        }
      }
    }
  }
}

// --------------------------- flash attention -------------------------------
// Swapped-QK 32x32: S^T = mfma32(A=K, B=Q), lane owns q-col q0+(l&31);
// softmax in-register; P -> A-frag via cvt_pk + permlane32_swap.
// QBLK=64 (32 q-rows/wave, 2 waves), KVBLK=64, double-buffered LDS (32 KB),
// global_load_lds staging, per-lane source XOR-swizzle chunk^(row&7),
// LDS linear dest; reads apply the same XOR -> 2-way banks (free).
// Grid 1024 = 32 bh x 32 tiles; bh = b&31 (XCD-locked), long tiles first.

__global__ __launch_bounds__(128, 2) void attn_kernel(
    const u16* __restrict__ Qb, const u16* __restrict__ Kb,
    const u16* __restrict__ Vtb, u16* __restrict__ attn) {
  constexpr int T = 2048;
  __shared__ u16 Ks[2][64 * 64];
  __shared__ u16 Vs[2][64 * 64];      // V^T tile: [d][kv]
  const int t = threadIdx.x;
  const int l = t & 63, w = t >> 6;
  const int c = l & 31, h = l >> 5;
  const int b = blockIdx.x;
  const int bh = b & 31;
  const int tile = 31 - (b >> 5);     // long tiles dispatched first
  const int ntile = tile + 1;
  const size_t base = (size_t)bh * T * 64;
  const u16* Qp = Qb + base;
  const u16* Kp = Kb + base;
  const u16* Vp = Vtb + base;          // [d][T]
  const int q0 = tile * 64 + w * 32;

  // Q fragments (B-operand): qf[dt], elem j = Q[q0+c][16dt+8h+j]
  bfrag qf[4];
#pragma unroll
  for (int dt = 0; dt < 4; ++dt)
    qf[dt] = *reinterpret_cast<const bfrag*>(Qp + (size_t)(q0 + c) * 64 + dt * 16 + 8 * h);

  f16v o[2] = {};                      // [nt] output accum (32q x 64d)
  float m_ = -1e30f, l_ = 0.f;

  // staging geometry: wave w covers rows [w*32, w*32+32), 4 calls x 1KB each
  const int srow = w * 32 + ((l & 63) >> 3);           // + 8j per call
  const int sw8  = ((t & 7) ^ ((t >> 3) & 7)) * 8;     // source chunk swizzle
  const int loff = w * 2048 + l * 8;                   // + 512j per call (u16)

#define STAGE(bufi, kvb_)                                                        \
  {                                                                              \
    _Pragma("unroll")                                                            \
    for (int j = 0; j < 4; ++j) {                                                \
      async_lds16(Kp + (size_t)((kvb_) + srow + 8 * j) * 64 + sw8,               \
                  &Ks[bufi][loff + 512 * j]);                                    \
      async_lds16(Vp + (size_t)(srow + 8 * j) * T + (kvb_) + sw8,                \
                  &Vs[bufi][loff + 512 * j]);                                    \
    }                                                                            \
  }

  STAGE(0, 0);
  __syncthreads();

  for (int it = 0; it < ntile; ++it) {
    const int cur = it & 1;
    if (it + 1 < ntile) STAGE(cur ^ 1, 64 * (it + 1));   // async prefetch
    const u16* ks = Ks[cur];
    const u16* vs = Vs[cur];

    // ---- S^T = K * Q : lane col q = q0 + c ----
    f16v s[2] = {};
#pragma unroll
    for (int kt = 0; kt < 2; ++kt)
#pragma unroll
      for (int dt = 0; dt < 4; ++dt) {
        const bfrag a = *reinterpret_cast<const bfrag*>(
            ks + (32 * kt + c) * 64 + (((2 * dt + h) ^ (c & 7)) * 8));
        s[kt] = MFMA32(a, qf[dt], s[kt]);
      }

    // ---- causal mask (diagonal tile only) ----
    if (it == ntile - 1) {
      const int kvb = 64 * it;
      const int qq = q0 + c;
#pragma unroll
      for (int kt = 0; kt < 2; ++kt)
#pragma unroll
        for (int r = 0; r < 16; ++r) {
          const int kk = kvb + 32 * kt + (r & 3) + 8 * (r >> 2) + 4 * h;
          if (kk > qq) s[kt][r] = -1e30f;
        }
    }

    // ---- online softmax, in-register (exp2 domain) ----
    {
      float pm = -1e30f;
#pragma unroll
      for (int kt = 0; kt < 2; ++kt)
#pragma unroll
        for (int r = 0; r < 16; ++r) pm = fmaxf(pm, s[kt][r]);
      pm = fmaxf(pm, __shfl_xor(pm, 32));
      if (!__all(pm <= m_ + 8.0f)) {       // T13 defer-max, THR=8
        const float mn = fmaxf(m_, pm);
        const float al = exp2f(m_ - mn);
        l_ *= al;
#pragma unroll
        for (int r = 0; r < 16; ++r) {
          const float ar = __shfl(al, (r & 3) + 8 * (r >> 2) + 4 * h);
          o[0][r] *= ar;
          o[1][r] *= ar;
        }
        m_ = mn;
      }
      float ps = 0.f;
#pragma unroll
      for (int kt = 0; kt < 2; ++kt)
#pragma unroll
        for (int r = 0; r < 16; ++r) {
          const float e = exp2f(s[kt][r] - m_);
          s[kt][r] = e;
          ps += e;
        }
      ps += __shfl_xor(ps, 32);
      l_ += ps;
    }

    // ---- P -> A-fragments: cvt_pk + permlane32_swap ----
    bfrag pa[4];
#pragma unroll
    for (int kt = 0; kt < 2; ++kt)
#pragma unroll
      for (int sub = 0; sub < 2; ++sub) {
        const int bs = 8 * sub;
        unsigned x1 = cvtpk(s[kt][bs + 0], s[kt][bs + 1]);
        unsigned y1 = cvtpk(s[kt][bs + 4], s[kt][bs + 5]);
        asm volatile("v_permlane32_swap_b32 %0, %1" : "+v"(x1), "+v"(y1));
        unsigned x2 = cvtpk(s[kt][bs + 2], s[kt][bs + 3]);
        unsigned y2 = cvtpk(s[kt][bs + 6], s[kt][bs + 7]);
        asm volatile("v_permlane32_swap_b32 %0, %1" : "+v"(x2), "+v"(y2));
        union { u32x4v wv; bfrag f; } u;
        u.wv[0] = x1; u.wv[1] = x2; u.wv[2] = y1; u.wv[3] = y2;
        pa[2 * kt + sub] = u.f;
      }

    // ---- O += P * V  (B-operand from V^T LDS) ----
#pragma unroll
    for (int nt = 0; nt < 2; ++nt)
#pragma unroll
      for (int k2 = 0; k2 < 4; ++k2) {
        const bfrag bv = *reinterpret_cast<const bfrag*>(
            vs + (32 * nt + c) * 64 + (((2 * k2 + h) ^ (c & 7)) * 8));
        o[nt] = MFMA32(pa[k2], bv, o[nt]);
      }

    __syncthreads();   // drains vmcnt (prefetch) + orders LDS reuse
  }

  // ---- epilogue: O / l, write [b][t][h*64+d] bf16 ----
  const int b_ = bh >> 4, hd = bh & 15;
  const float linv = 1.0f / l_;
#pragma unroll
  for (int r = 0; r < 16; ++r) {
    const int row = (r & 3) + 8 * (r >> 2) + 4 * h;
    const float lr = __shfl(linv, row);
    const int tq = q0 + row;
#pragma unroll
    for (int nt = 0; nt < 2; ++nt) {
      const int col = hd * 64 + 32 * nt + c;
      attn[((size_t)(b_ * T + tq)) * 1024 + col] = f2bf(o[nt][r] * lr);
    }
  }
#undef STAGE
}

// --------------------------- launcher --------------------------------------

extern "C" void kernel_launch(void* const* d_in, const int* in_sizes, int n_in,
                              void* d_out, int out_size, void* d_ws, size_t ws_size,
                              hipStream_t stream) {
  const float* x      = (const float*)d_in[0];
  const float* W_attn = (const float*)d_in[1];
  const float* b_attn = (const float*)d_in[2];
  const float* W_proj = (const float*)d_in[3];
  const float* b_proj = (const float*)d_in[4];
  float* out = (float*)d_out;
  char* ws = (char*)d_ws;
  // ws layout (48 MiB total)
  u16* xb   = (u16*)(ws);                       // [4096][1024] bf16   8 MiB
  u16* Wat  = (u16*)(ws + (8u  << 20));         // [3072][1024] bf16   6 MiB
  u16* Wpt  = (u16*)(ws + (14u << 20));         // [1024][1024] bf16   2 MiB
  u16* Qb   = (u16*)(ws + (16u << 20));         // [bh][t][d] bf16     8 MiB
  u16* Kb   = (u16*)(ws + (24u << 20));         // [bh][t][d]          8 MiB
  u16* Vtb  = (u16*)(ws + (32u << 20));         // [bh][d][t] (V^T)    8 MiB
  u16* attn = (u16*)(ws + (40u << 20));         // [4096][1024] bf16   8 MiB

  cast_bf16_kernel<<<4096, 256, 0, stream>>>(x, xb, 4096 * 1024);
  transpose_cast_kernel<<<dim3(96, 32), dim3(32, 8), 0, stream>>>(W_attn, Wat, 1024, 3072);
  transpose_cast_kernel<<<dim3(32, 32), dim3(32, 8), 0, stream>>>(W_proj, Wpt, 1024, 1024);
  gemm_kernel<0><<<dim3(24, 32), 256, 0, stream>>>(xb, Wat, b_attn, nullptr, Qb, Kb, Vtb);
  attn_kernel<<<1024, 128, 0, stream>>>(Qb, Kb, Vtb, attn);
  gemm_kernel<1><<<dim3(8, 32), 256, 0, stream>>>(attn, Wpt, b_proj, out, nullptr, nullptr, nullptr);
}